// Round 2
// baseline (294.885 us; speedup 1.0000x reference)
//
#include <hip/hip_runtime.h>

#define BB 16
#define HH 256
#define WW 256
#define CC 16
#define HID 128
#define TS 16
#define NPIX ((size_t)BB * HH * WW)
#define KEXP 160   // 9 taps x 16 ch = 144, padded to 160 (tap 9 = zero weights)
#define XSTR 24    // xt pixel stride in bf16 (16 ch + 8 pad, 48 B)
#define HSTR 40    // H row stride in bf16 (32 + 8 pad)

typedef __attribute__((ext_vector_type(8))) short short8;
typedef __attribute__((ext_vector_type(4))) float floatx4;

__device__ inline unsigned int f2bf(float f) {
    unsigned int u = __float_as_uint(f);
    return (u + 0x7FFFu + ((u >> 16) & 1u)) >> 16;   // RNE (prep only)
}
// truncating bf16x2 pack: one v_perm_b32. mem order: lo then hi.
__device__ inline unsigned int packtr(float lo, float hi) {
    return __builtin_amdgcn_perm(__float_as_uint(hi), __float_as_uint(lo), 0x07060302u);
}

// ---------------------------------------------------------------------------
// prep: w0e[n][t*16+c] = sobel-folded first-layer weights (128 x 160 bf16,
// cols 144..159 zero). w1b[o][c_hid] = 16 x 128 bf16.
// ---------------------------------------------------------------------------
__global__ void prep(const float* __restrict__ w0, const float* __restrict__ w1,
                     unsigned short* __restrict__ w0e, unsigned short* __restrict__ w1b) {
    int i = blockIdx.x * blockDim.x + threadIdx.x;
    if (i < HID * KEXP) {
        int n = i / KEXP, k = i % KEXP;
        int t = k >> 4, c = k & 15;
        float v = 0.f;
        if (t < 9) {
            int dy = t / 3, dx = t % 3;
            float id = (t == 4) ? 1.f : 0.f;
            float sx = (float)(dx - 1) * ((dy == 1) ? 2.f : 1.f) * 0.125f;
            float sy = (float)(dy - 1) * ((dx == 1) ? 2.f : 1.f) * 0.125f;
            v = w0[n * 48 + 3 * c] * id + w0[n * 48 + 3 * c + 1] * sx
              + w0[n * 48 + 3 * c + 2] * sy;
        }
        w0e[i] = (unsigned short)f2bf(v);
    }
    if (i < CC * HID) w1b[i] = (unsigned short)f2bf(w1[i]);
}

// ---------------------------------------------------------------------------
// pass1: stage x tile (bf16) -> MFMA does conv+MLP fused (K=160 gathered taps)
// GEMM1: H^T[n][p] = sum_k W0e[n][k] Xg[p][k]; GEMM2 via per-wave LDS H buffer
// (r0 structure — known-good schedule). Change vs r0: Hb is SINGLE-buffered.
// WAR safety: same-wave DS ops execute in order, so the Bh read of iteration i
// completes before iteration i+1's H-writes execute; compiler keeps program
// order (may-alias through Hw). LDS: xt 15552 + at 1296 + Hb 5120 = 21968 B
// -> 7 blocks/CU (was 5 at 27136 B). __launch_bounds__(256,7) caps VGPR at 73.
// C/D layout: col=lane&15, row=quad*4+reg (m89/m91-verified)
// ---------------------------------------------------------------------------
__global__ __launch_bounds__(256, 7)
void pass1(const float* __restrict__ x, const unsigned short* __restrict__ w0e,
           const unsigned short* __restrict__ w1b, const float* __restrict__ rand_mask,
           float* __restrict__ xn_out, float* __restrict__ alpha_out,
           float* __restrict__ pre_out)
{
    __shared__ unsigned short xt[18 * 18 * XSTR];          // bf16 halo tile
    __shared__ float at[18 * 18];                          // alpha (ch3) fp32 plane
    __shared__ unsigned short Hb[4][16 * HSTR];            // per-wave H buffer (single)

    const int tx = threadIdx.x, ty = threadIdx.y;
    const int bx = blockIdx.x * TS, by = blockIdx.y * TS, b = blockIdx.z;
    const int tid = ty * TS + tx;
    const float* xb = x + (size_t)b * HH * WW * CC;

    // ---- stage halo tile: fp32 global -> bf16 LDS (+ alpha plane) ----
    for (int idx = tid; idx < 18 * 18 * 4; idx += 256) {
        int cq = idx & 3, p = idx >> 2;
        int lyy = p / 18, lxx = p % 18;
        int gy = by + lyy - 1, gx = bx + lxx - 1;
        float4 v = make_float4(0.f, 0.f, 0.f, 0.f);
        if (gy >= 0 && gy < HH && gx >= 0 && gx < WW)
            v = *(const float4*)(xb + (size_t)(gy * WW + gx) * CC + cq * 4);
        *(uint2*)(xt + p * XSTR + cq * 4) = make_uint2(packtr(v.x, v.y), packtr(v.z, v.w));
        if (cq == 0) at[p] = v.w;   // channel 3
    }
    __syncthreads();

    // ---- pre_life: 3x3 max of alpha > 0.1 ----
    {
        float m = -1.f;
        #pragma unroll
        for (int dy = 0; dy < 3; ++dy) {
            const float* r = at + (ty + dy) * 18 + tx;
            m = fmaxf(m, fmaxf(fmaxf(r[0], r[1]), r[2]));
        }
        const size_t pix0 = (size_t)b * HH * WW + (size_t)(by + ty) * WW + (bx + tx);
        pre_out[pix0] = (m > 0.1f) ? 1.f : 0.f;
    }

    // ---- MFMA phase: wave w owns pixels [64w, 64w+64), 4 nt-tiles of 16 ----
    const int w = tid >> 6, lane = tid & 63;
    const int quad = lane >> 4, lr = lane & 15;
    const int qh = quad >> 1, c0 = (quad & 1) * 8;

    // per-lane tap offsets (bf16 units) for ks=0..4: t = 2ks + qh (clamped to 8)
    // off(t) = ((t/3)*18 + t%3) * XSTR
    const int off0 = qh ? (1 * XSTR) : 0;
    const int off1 = qh ? (18 * XSTR + 0 * XSTR) : (2 * XSTR);
    const int off2 = qh ? (18 * XSTR + 2 * XSTR) : (18 * XSTR + 1 * XSTR);
    const int off3 = qh ? (36 * XSTR + 1 * XSTR) : (36 * XSTR + 0 * XSTR);
    const int off4 = 36 * XSTR + 2 * XSTR;   // t=8 both (qh=1 side has zero weights)

    floatx4 dacc[4] = {{0.f,0.f,0.f,0.f},{0.f,0.f,0.f,0.f},
                       {0.f,0.f,0.f,0.f},{0.f,0.f,0.f,0.f}};

    unsigned short* Hw = &Hb[w][0];

    #pragma unroll 1
    for (int q = 0; q < 4; ++q) {
        // A-frags for this hid-quarter: 2 m-tiles x 5 k-steps (40 VGPRs)
        short8 A0[2][5];
        #pragma unroll
        for (int mt = 0; mt < 2; ++mt)
            #pragma unroll
            for (int ks = 0; ks < 5; ++ks)
                A0[mt][ks] = *(const short8*)(w0e + (q * 32 + mt * 16 + lr) * KEXP
                                              + ks * 32 + quad * 8);
        const short8 A1q = *(const short8*)(w1b + lr * HID + q * 32 + quad * 8);

        #pragma unroll
        for (int nt = 0; nt < 4; ++nt) {
            const int base = ((w * 4 + nt) * 18 + lr) * XSTR + c0;
            short8 Bf0 = *(const short8*)(xt + base + off0);
            short8 Bf1 = *(const short8*)(xt + base + off1);
            short8 Bf2 = *(const short8*)(xt + base + off2);
            short8 Bf3 = *(const short8*)(xt + base + off3);
            short8 Bf4 = *(const short8*)(xt + base + off4);

            #pragma unroll
            for (int mt = 0; mt < 2; ++mt) {
                floatx4 acc = {0.f, 0.f, 0.f, 0.f};
                acc = __builtin_amdgcn_mfma_f32_16x16x32_bf16(A0[mt][0], Bf0, acc, 0, 0, 0);
                acc = __builtin_amdgcn_mfma_f32_16x16x32_bf16(A0[mt][1], Bf1, acc, 0, 0, 0);
                acc = __builtin_amdgcn_mfma_f32_16x16x32_bf16(A0[mt][2], Bf2, acc, 0, 0, 0);
                acc = __builtin_amdgcn_mfma_f32_16x16x32_bf16(A0[mt][3], Bf3, acc, 0, 0, 0);
                acc = __builtin_amdgcn_mfma_f32_16x16x32_bf16(A0[mt][4], Bf4, acc, 0, 0, 0);
                // lane holds H[pixel=lr][hid = q*32 + mt*16 + quad*4 + r]
                unsigned int lo = packtr(fmaxf(acc[0], 0.f), fmaxf(acc[1], 0.f));
                unsigned int hi = packtr(fmaxf(acc[2], 0.f), fmaxf(acc[3], 0.f));
                *(uint2*)(Hw + lr * HSTR + mt * 16 + quad * 4) = make_uint2(lo, hi);
            }
            // RAW: cross-lane H writes must land before B-read. (In-order DS
            // makes the iter->iter WAR on the single buffer safe: this read
            // executes before next iteration's writes.)
            asm volatile("s_waitcnt lgkmcnt(0)" ::: "memory");
            short8 Bh = *(const short8*)(Hw + lr * HSTR + quad * 8);
            dacc[nt] = __builtin_amdgcn_mfma_f32_16x16x32_bf16(A1q, Bh, dacc[nt], 0, 0, 0);
        }
    }

    // ---- epilogue: lane holds dx[pixel = w*64+nt*16+lr][o = quad*4+r] ----
    #pragma unroll
    for (int nt = 0; nt < 4; ++nt) {
        const int gy = by + w * 4 + nt, gx = bx + lr;
        const size_t pix = (size_t)b * HH * WW + (size_t)gy * WW + gx;
        const float upd = (rand_mask[pix] <= 0.5f) ? 1.f : 0.f;
        const float4 xc = *(const float4*)(x + pix * CC + quad * 4);
        float4 xn;
        xn.x = xc.x + dacc[nt][0] * upd;
        xn.y = xc.y + dacc[nt][1] * upd;
        xn.z = xc.z + dacc[nt][2] * upd;
        xn.w = xc.w + dacc[nt][3] * upd;
        *(float4*)(xn_out + pix * CC + quad * 4) = xn;
        if (quad == 0) alpha_out[pix] = xn.w;   // channel 3
    }
}

// ---------------------------------------------------------------------------
// pass2: out already holds xn; zero only dead pixels (life==0).
// 4 px/thread, 64x16 tile, float4 alpha/pre loads -> 1024 blocks.
// ---------------------------------------------------------------------------
#define P2W 64
#define P2H 16
__global__ __launch_bounds__(256)
void pass2(const float* __restrict__ alpha, const float* __restrict__ pre,
           float* __restrict__ out)
{
    __shared__ float at2[18][66];
    const int tx = threadIdx.x, ty = threadIdx.y;   // 16 x 16
    const int bx = blockIdx.x * P2W, by = blockIdx.y * P2H, b = blockIdx.z;
    const int tid = ty * 16 + tx;
    const float* ab = alpha + (size_t)b * HH * WW;

    // interior: 18 rows x 16 float4 segs (cols bx..bx+63 -> at2 cols 1..64)
    for (int idx = tid; idx < 18 * 16; idx += 256) {
        int r = idx >> 4, s = idx & 15;
        int gy = by + r - 1;
        float4 v = make_float4(0.f, 0.f, 0.f, 0.f);
        if (gy >= 0 && gy < HH)
            v = *(const float4*)(ab + (size_t)gy * WW + (bx + s * 4));
        at2[r][1 + s * 4 + 0] = v.x;
        at2[r][1 + s * 4 + 1] = v.y;
        at2[r][1 + s * 4 + 2] = v.z;
        at2[r][1 + s * 4 + 3] = v.w;
    }
    // halo edges: 18 rows x 2 cols
    if (tid < 36) {
        int r = tid >> 1, e = tid & 1;
        int gy = by + r - 1, gx = e ? (bx + P2W) : (bx - 1);
        float v = 0.f;
        if (gy >= 0 && gy < HH && gx >= 0 && gx < WW) v = ab[(size_t)gy * WW + gx];
        at2[r][e ? 65 : 0] = v;
    }
    __syncthreads();

    const int x0 = tx * 4;
    float vm0 = -1.f, vm1 = -1.f, vm2 = -1.f, vm3 = -1.f;
    #pragma unroll
    for (int dr = 0; dr < 3; ++dr) {
        const float* rp = &at2[ty + dr][x0];   // col x0 == gx (bx+x0-1)
        float a0 = rp[0], a1 = rp[1], a2 = rp[2];
        float a3 = rp[3], a4 = rp[4], a5 = rp[5];
        vm0 = fmaxf(vm0, fmaxf(fmaxf(a0, a1), a2));
        vm1 = fmaxf(vm1, fmaxf(fmaxf(a1, a2), a3));
        vm2 = fmaxf(vm2, fmaxf(fmaxf(a2, a3), a4));
        vm3 = fmaxf(vm3, fmaxf(fmaxf(a3, a4), a5));
    }

    const size_t pix0 = (size_t)b * HH * WW + (size_t)(by + ty) * WW + (bx + x0);
    const float4 pr = *(const float4*)(pre + pix0);
    const float vms[4] = {vm0, vm1, vm2, vm3};
    const float prs[4] = {pr.x, pr.y, pr.z, pr.w};
    #pragma unroll
    for (int j = 0; j < 4; ++j) {
        if (!(vms[j] > 0.1f && prs[j] > 0.5f)) {
            float4 z = make_float4(0.f, 0.f, 0.f, 0.f);
            float4* o4 = (float4*)(out + (pix0 + j) * CC);
            o4[0] = z; o4[1] = z; o4[2] = z; o4[3] = z;
        }
    }
}

extern "C" void kernel_launch(void* const* d_in, const int* in_sizes, int n_in,
                              void* d_out, int out_size, void* d_ws, size_t ws_size,
                              hipStream_t stream) {
    const float* x  = (const float*)d_in[0];
    const float* w0 = (const float*)d_in[1];
    const float* w1 = (const float*)d_in[2];
    const float* rm = (const float*)d_in[3];
    float* out = (float*)d_out;

    float* ws    = (float*)d_ws;
    float* alpha = ws;                         // B*H*W floats
    float* pre   = ws + NPIX;                  // B*H*W floats
    unsigned short* w0e = (unsigned short*)(ws + 2 * NPIX);  // 128*160 bf16
    unsigned short* w1b = w0e + HID * KEXP;                  // 16*128 bf16

    prep<<<(HID * KEXP + 255) / 256, 256, 0, stream>>>(w0, w1, w0e, w1b);

    dim3 grid(WW / TS, HH / TS, BB);
    dim3 blk(TS, TS);
    pass1<<<grid, blk, 0, stream>>>(x, w0e, w1b, rm, out, alpha, pre);

    dim3 grid2(WW / P2W, HH / P2H, BB);
    pass2<<<grid2, dim3(16, 16), 0, stream>>>(alpha, pre, out);
}

// Round 3
// 233.356 us; speedup vs baseline: 1.2637x; 1.2637x over previous
//
#include <hip/hip_runtime.h>

#define BB 16
#define HH 256
#define WW 256
#define CC 16
#define HID 128
#define TS 16
#define NPIX ((size_t)BB * HH * WW)
#define KEXP 160   // 9 taps x 16 ch = 144, padded to 160 (tap 9 = zero weights)
#define XSTR 26    // xt pixel stride in bf16 (16 ch + 10 pad, 52 B = 13 dwords, gcd(13,32)=1)
#define HSTR 34    // H row stride in bf16 (32 + 2 pad, 68 B = 17 dwords, gcd(17,32)=1)

typedef __attribute__((ext_vector_type(8))) short short8;
typedef __attribute__((ext_vector_type(4))) float floatx4;

__device__ inline unsigned int f2bf(float f) {
    unsigned int u = __float_as_uint(f);
    return (u + 0x7FFFu + ((u >> 16) & 1u)) >> 16;   // RNE (prep only)
}
// truncating bf16x2 pack: one v_perm_b32. mem order: lo then hi.
__device__ inline unsigned int packtr(float lo, float hi) {
    return __builtin_amdgcn_perm(__float_as_uint(hi), __float_as_uint(lo), 0x07060302u);
}

// ---------------------------------------------------------------------------
// prep: w0e[n][t*16+c] = sobel-folded first-layer weights (128 x 160 bf16,
// cols 144..159 zero). w1b[o][c_hid] = 16 x 128 bf16.
// ---------------------------------------------------------------------------
__global__ void prep(const float* __restrict__ w0, const float* __restrict__ w1,
                     unsigned short* __restrict__ w0e, unsigned short* __restrict__ w1b) {
    int i = blockIdx.x * blockDim.x + threadIdx.x;
    if (i < HID * KEXP) {
        int n = i / KEXP, k = i % KEXP;
        int t = k >> 4, c = k & 15;
        float v = 0.f;
        if (t < 9) {
            int dy = t / 3, dx = t % 3;
            float id = (t == 4) ? 1.f : 0.f;
            float sx = (float)(dx - 1) * ((dy == 1) ? 2.f : 1.f) * 0.125f;
            float sy = (float)(dy - 1) * ((dx == 1) ? 2.f : 1.f) * 0.125f;
            v = w0[n * 48 + 3 * c] * id + w0[n * 48 + 3 * c + 1] * sx
              + w0[n * 48 + 3 * c + 2] * sy;
        }
        w0e[i] = (unsigned short)f2bf(v);
    }
    if (i < CC * HID) w1b[i] = (unsigned short)f2bf(w1[i]);
}

// ---------------------------------------------------------------------------
// pass1: r0 structure (known-good schedule, VGPR~60, NO launch_bounds cap —
// the ",7" min-waves arg in r2 forced VGPR=36 -> 600 MB scratch spill).
// Changes vs r0:
//  - Hb single-buffered (r2-proven correct): same-wave DS ops execute in
//    order, so iter i's Bh read completes before iter i+1's H-writes.
//    LDS 27136 -> 22496 B => 7 blocks/CU (r0: 6).
//  - Odd-dword LDS strides: XSTR 24->26 (13 dwords), HSTR 40->34 (17 dwords).
//    r0's 12/20-dword strides alias lr-lanes onto 8 banks (9.0M conflict
//    cycles); gcd(stride,32)=1 spreads all 16 lr values across distinct banks.
// C/D layout: col=lane&15, row=quad*4+reg (m89/m91-verified)
// ---------------------------------------------------------------------------
__global__ __launch_bounds__(256)
void pass1(const float* __restrict__ x, const unsigned short* __restrict__ w0e,
           const unsigned short* __restrict__ w1b, const float* __restrict__ rand_mask,
           float* __restrict__ xn_out, float* __restrict__ alpha_out,
           float* __restrict__ pre_out)
{
    __shared__ unsigned short xt[18 * 18 * XSTR];          // bf16 halo tile
    __shared__ float at[18 * 18];                          // alpha (ch3) fp32 plane
    __shared__ unsigned short Hb[4][16 * HSTR];            // per-wave H buffer (single)

    const int tx = threadIdx.x, ty = threadIdx.y;
    const int bx = blockIdx.x * TS, by = blockIdx.y * TS, b = blockIdx.z;
    const int tid = ty * TS + tx;
    const float* xb = x + (size_t)b * HH * WW * CC;

    // ---- stage halo tile: fp32 global -> bf16 LDS (+ alpha plane) ----
    for (int idx = tid; idx < 18 * 18 * 4; idx += 256) {
        int cq = idx & 3, p = idx >> 2;
        int lyy = p / 18, lxx = p % 18;
        int gy = by + lyy - 1, gx = bx + lxx - 1;
        float4 v = make_float4(0.f, 0.f, 0.f, 0.f);
        if (gy >= 0 && gy < HH && gx >= 0 && gx < WW)
            v = *(const float4*)(xb + (size_t)(gy * WW + gx) * CC + cq * 4);
        *(uint2*)(xt + p * XSTR + cq * 4) = make_uint2(packtr(v.x, v.y), packtr(v.z, v.w));
        if (cq == 0) at[p] = v.w;   // channel 3
    }
    __syncthreads();

    // ---- pre_life: 3x3 max of alpha > 0.1 ----
    {
        float m = -1.f;
        #pragma unroll
        for (int dy = 0; dy < 3; ++dy) {
            const float* r = at + (ty + dy) * 18 + tx;
            m = fmaxf(m, fmaxf(fmaxf(r[0], r[1]), r[2]));
        }
        const size_t pix0 = (size_t)b * HH * WW + (size_t)(by + ty) * WW + (bx + tx);
        pre_out[pix0] = (m > 0.1f) ? 1.f : 0.f;
    }

    // ---- MFMA phase: wave w owns pixels [64w, 64w+64), 4 nt-tiles of 16 ----
    const int w = tid >> 6, lane = tid & 63;
    const int quad = lane >> 4, lr = lane & 15;
    const int qh = quad >> 1, c0 = (quad & 1) * 8;

    // per-lane tap offsets (bf16 units) for ks=0..4: t = 2ks + qh (clamped to 8)
    // off(t) = ((t/3)*18 + t%3) * XSTR
    const int off0 = qh ? (1 * XSTR) : 0;
    const int off1 = qh ? (18 * XSTR + 0 * XSTR) : (2 * XSTR);
    const int off2 = qh ? (18 * XSTR + 2 * XSTR) : (18 * XSTR + 1 * XSTR);
    const int off3 = qh ? (36 * XSTR + 1 * XSTR) : (36 * XSTR + 0 * XSTR);
    const int off4 = 36 * XSTR + 2 * XSTR;   // t=8 both (qh=1 side has zero weights)

    floatx4 dacc[4] = {{0.f,0.f,0.f,0.f},{0.f,0.f,0.f,0.f},
                       {0.f,0.f,0.f,0.f},{0.f,0.f,0.f,0.f}};

    unsigned short* Hw = &Hb[w][0];

    #pragma unroll 1
    for (int q = 0; q < 4; ++q) {
        // A-frags for this hid-quarter: 2 m-tiles x 5 k-steps (40 VGPRs)
        short8 A0[2][5];
        #pragma unroll
        for (int mt = 0; mt < 2; ++mt)
            #pragma unroll
            for (int ks = 0; ks < 5; ++ks)
                A0[mt][ks] = *(const short8*)(w0e + (q * 32 + mt * 16 + lr) * KEXP
                                              + ks * 32 + quad * 8);
        const short8 A1q = *(const short8*)(w1b + lr * HID + q * 32 + quad * 8);

        #pragma unroll
        for (int nt = 0; nt < 4; ++nt) {
            const int base = ((w * 4 + nt) * 18 + lr) * XSTR + c0;
            short8 Bf0 = *(const short8*)(xt + base + off0);
            short8 Bf1 = *(const short8*)(xt + base + off1);
            short8 Bf2 = *(const short8*)(xt + base + off2);
            short8 Bf3 = *(const short8*)(xt + base + off3);
            short8 Bf4 = *(const short8*)(xt + base + off4);

            #pragma unroll
            for (int mt = 0; mt < 2; ++mt) {
                floatx4 acc = {0.f, 0.f, 0.f, 0.f};
                acc = __builtin_amdgcn_mfma_f32_16x16x32_bf16(A0[mt][0], Bf0, acc, 0, 0, 0);
                acc = __builtin_amdgcn_mfma_f32_16x16x32_bf16(A0[mt][1], Bf1, acc, 0, 0, 0);
                acc = __builtin_amdgcn_mfma_f32_16x16x32_bf16(A0[mt][2], Bf2, acc, 0, 0, 0);
                acc = __builtin_amdgcn_mfma_f32_16x16x32_bf16(A0[mt][3], Bf3, acc, 0, 0, 0);
                acc = __builtin_amdgcn_mfma_f32_16x16x32_bf16(A0[mt][4], Bf4, acc, 0, 0, 0);
                // lane holds H[pixel=lr][hid = q*32 + mt*16 + quad*4 + r]
                unsigned int lo = packtr(fmaxf(acc[0], 0.f), fmaxf(acc[1], 0.f));
                unsigned int hi = packtr(fmaxf(acc[2], 0.f), fmaxf(acc[3], 0.f));
                *(uint2*)(Hw + lr * HSTR + mt * 16 + quad * 4) = make_uint2(lo, hi);
            }
            // RAW: cross-lane H writes must land before B-read. (In-order DS
            // per wave makes the iter->iter WAR on the single buffer safe.)
            asm volatile("s_waitcnt lgkmcnt(0)" ::: "memory");
            short8 Bh = *(const short8*)(Hw + lr * HSTR + quad * 8);
            dacc[nt] = __builtin_amdgcn_mfma_f32_16x16x32_bf16(A1q, Bh, dacc[nt], 0, 0, 0);
        }
    }

    // ---- epilogue: lane holds dx[pixel = w*64+nt*16+lr][o = quad*4+r] ----
    #pragma unroll
    for (int nt = 0; nt < 4; ++nt) {
        const int gy = by + w * 4 + nt, gx = bx + lr;
        const size_t pix = (size_t)b * HH * WW + (size_t)gy * WW + gx;
        const float upd = (rand_mask[pix] <= 0.5f) ? 1.f : 0.f;
        const float4 xc = *(const float4*)(x + pix * CC + quad * 4);
        float4 xn;
        xn.x = xc.x + dacc[nt][0] * upd;
        xn.y = xc.y + dacc[nt][1] * upd;
        xn.z = xc.z + dacc[nt][2] * upd;
        xn.w = xc.w + dacc[nt][3] * upd;
        *(float4*)(xn_out + pix * CC + quad * 4) = xn;
        if (quad == 0) alpha_out[pix] = xn.w;   // channel 3
    }
}

// ---------------------------------------------------------------------------
// pass2: out already holds xn; zero only dead pixels (life==0).
// 4 px/thread, 64x16 tile, float4 alpha/pre loads -> 1024 blocks.
// ---------------------------------------------------------------------------
#define P2W 64
#define P2H 16
__global__ __launch_bounds__(256)
void pass2(const float* __restrict__ alpha, const float* __restrict__ pre,
           float* __restrict__ out)
{
    __shared__ float at2[18][66];
    const int tx = threadIdx.x, ty = threadIdx.y;   // 16 x 16
    const int bx = blockIdx.x * P2W, by = blockIdx.y * P2H, b = blockIdx.z;
    const int tid = ty * 16 + tx;
    const float* ab = alpha + (size_t)b * HH * WW;

    // interior: 18 rows x 16 float4 segs (cols bx..bx+63 -> at2 cols 1..64)
    for (int idx = tid; idx < 18 * 16; idx += 256) {
        int r = idx >> 4, s = idx & 15;
        int gy = by + r - 1;
        float4 v = make_float4(0.f, 0.f, 0.f, 0.f);
        if (gy >= 0 && gy < HH)
            v = *(const float4*)(ab + (size_t)gy * WW + (bx + s * 4));
        at2[r][1 + s * 4 + 0] = v.x;
        at2[r][1 + s * 4 + 1] = v.y;
        at2[r][1 + s * 4 + 2] = v.z;
        at2[r][1 + s * 4 + 3] = v.w;
    }
    // halo edges: 18 rows x 2 cols
    if (tid < 36) {
        int r = tid >> 1, e = tid & 1;
        int gy = by + r - 1, gx = e ? (bx + P2W) : (bx - 1);
        float v = 0.f;
        if (gy >= 0 && gy < HH && gx >= 0 && gx < WW) v = ab[(size_t)gy * WW + gx];
        at2[r][e ? 65 : 0] = v;
    }
    __syncthreads();

    const int x0 = tx * 4;
    float vm0 = -1.f, vm1 = -1.f, vm2 = -1.f, vm3 = -1.f;
    #pragma unroll
    for (int dr = 0; dr < 3; ++dr) {
        const float* rp = &at2[ty + dr][x0];   // col x0 == gx (bx+x0-1)
        float a0 = rp[0], a1 = rp[1], a2 = rp[2];
        float a3 = rp[3], a4 = rp[4], a5 = rp[5];
        vm0 = fmaxf(vm0, fmaxf(fmaxf(a0, a1), a2));
        vm1 = fmaxf(vm1, fmaxf(fmaxf(a1, a2), a3));
        vm2 = fmaxf(vm2, fmaxf(fmaxf(a2, a3), a4));
        vm3 = fmaxf(vm3, fmaxf(fmaxf(a3, a4), a5));
    }

    const size_t pix0 = (size_t)b * HH * WW + (size_t)(by + ty) * WW + (bx + x0);
    const float4 pr = *(const float4*)(pre + pix0);
    const float vms[4] = {vm0, vm1, vm2, vm3};
    const float prs[4] = {pr.x, pr.y, pr.z, pr.w};
    #pragma unroll
    for (int j = 0; j < 4; ++j) {
        if (!(vms[j] > 0.1f && prs[j] > 0.5f)) {
            float4 z = make_float4(0.f, 0.f, 0.f, 0.f);
            float4* o4 = (float4*)(out + (pix0 + j) * CC);
            o4[0] = z; o4[1] = z; o4[2] = z; o4[3] = z;
        }
    }
}

extern "C" void kernel_launch(void* const* d_in, const int* in_sizes, int n_in,
                              void* d_out, int out_size, void* d_ws, size_t ws_size,
                              hipStream_t stream) {
    const float* x  = (const float*)d_in[0];
    const float* w0 = (const float*)d_in[1];
    const float* w1 = (const float*)d_in[2];
    const float* rm = (const float*)d_in[3];
    float* out = (float*)d_out;

    float* ws    = (float*)d_ws;
    float* alpha = ws;                         // B*H*W floats
    float* pre   = ws + NPIX;                  // B*H*W floats
    unsigned short* w0e = (unsigned short*)(ws + 2 * NPIX);  // 128*160 bf16
    unsigned short* w1b = w0e + HID * KEXP;                  // 16*128 bf16

    prep<<<(HID * KEXP + 255) / 256, 256, 0, stream>>>(w0, w1, w0e, w1b);

    dim3 grid(WW / TS, HH / TS, BB);
    dim3 blk(TS, TS);
    pass1<<<grid, blk, 0, stream>>>(x, w0e, w1b, rm, out, alpha, pre);

    dim3 grid2(WW / P2W, HH / P2H, BB);
    pass2<<<grid2, dim3(16, 16), 0, stream>>>(alpha, pre, out);
}

// Round 4
// 211.783 us; speedup vs baseline: 1.3924x; 1.1019x over previous
//
#include <hip/hip_runtime.h>

#define BB 16
#define HH 256
#define WW 256
#define CC 16
#define HID 128
#define TS 16
#define NPIX ((size_t)BB * HH * WW)
#define KEXP 160   // 9 taps x 16 ch = 144, padded to 160 (tap 9 = zero weights)
#define XSTR 24    // xt pixel stride in bf16 (48 B: 16B-aligned, 2-way bank alias = free)
#define HSTR 40    // H row stride in bf16 (80 B: 16B-aligned)

typedef __attribute__((ext_vector_type(8))) short short8;
typedef __attribute__((ext_vector_type(4))) float floatx4;

__device__ inline unsigned int f2bf(float f) {
    unsigned int u = __float_as_uint(f);
    return (u + 0x7FFFu + ((u >> 16) & 1u)) >> 16;   // RNE (prep only)
}
// truncating bf16x2 pack: one v_perm_b32. mem order: lo then hi.
__device__ inline unsigned int packtr(float lo, float hi) {
    return __builtin_amdgcn_perm(__float_as_uint(hi), __float_as_uint(lo), 0x07060302u);
}

// ---------------------------------------------------------------------------
// prep: w0e[n][t*16+c] = sobel-folded first-layer weights (128 x 160 bf16,
// cols 144..159 zero). w1b[o][c_hid] = 16 x 128 bf16.
// ---------------------------------------------------------------------------
__global__ void prep(const float* __restrict__ w0, const float* __restrict__ w1,
                     unsigned short* __restrict__ w0e, unsigned short* __restrict__ w1b) {
    int i = blockIdx.x * blockDim.x + threadIdx.x;
    if (i < HID * KEXP) {
        int n = i / KEXP, k = i % KEXP;
        int t = k >> 4, c = k & 15;
        float v = 0.f;
        if (t < 9) {
            int dy = t / 3, dx = t % 3;
            float id = (t == 4) ? 1.f : 0.f;
            float sx = (float)(dx - 1) * ((dy == 1) ? 2.f : 1.f) * 0.125f;
            float sy = (float)(dy - 1) * ((dx == 1) ? 2.f : 1.f) * 0.125f;
            v = w0[n * 48 + 3 * c] * id + w0[n * 48 + 3 * c + 1] * sx
              + w0[n * 48 + 3 * c + 2] * sy;
        }
        w0e[i] = (unsigned short)f2bf(v);
    }
    if (i < CC * HID) w1b[i] = (unsigned short)f2bf(w1[i]);
}

// ---------------------------------------------------------------------------
// pass1: r0 structure + two changes:
//  (1) Hb single-buffered (r2/r3-proven: same-wave DS ops complete in order,
//      so iter i's Bh read retires before iter i+1's H-writes execute).
//      LDS 27136 -> 22016 B => 7 blocks/CU.
//  (2) No manual lgkmcnt(0) drain. Hb writes and the Bh read may-alias, so
//      the compiler preserves DS order; in-order LDS completion means the
//      compiler's counted wait on Bh implies the writes landed. Next nt's
//      Bf frags are prefetched between the Bh read and GEMM2 (double-buffer
//      Bf[2][5], compile-time nt&1), so their latency hides under GEMM2 +
//      the next GEMM1 instead of being serially exposed.
// Strides are r0's (16B-aligned: r3 proved odd-dword strides split every
// b128 access). C/D layout: col=lane&15, row=quad*4+reg (m89/m91-verified).
// ---------------------------------------------------------------------------
__global__ __launch_bounds__(256)
void pass1(const float* __restrict__ x, const unsigned short* __restrict__ w0e,
           const unsigned short* __restrict__ w1b, const float* __restrict__ rand_mask,
           float* __restrict__ xn_out, float* __restrict__ alpha_out,
           float* __restrict__ pre_out)
{
    __shared__ unsigned short xt[18 * 18 * XSTR];          // bf16 halo tile
    __shared__ float at[18 * 18];                          // alpha (ch3) fp32 plane
    __shared__ unsigned short Hb[4][16 * HSTR];            // per-wave H buffer (single)

    const int tx = threadIdx.x, ty = threadIdx.y;
    const int bx = blockIdx.x * TS, by = blockIdx.y * TS, b = blockIdx.z;
    const int tid = ty * TS + tx;
    const float* xb = x + (size_t)b * HH * WW * CC;

    // ---- stage halo tile: fp32 global -> bf16 LDS (+ alpha plane) ----
    for (int idx = tid; idx < 18 * 18 * 4; idx += 256) {
        int cq = idx & 3, p = idx >> 2;
        int lyy = p / 18, lxx = p % 18;
        int gy = by + lyy - 1, gx = bx + lxx - 1;
        float4 v = make_float4(0.f, 0.f, 0.f, 0.f);
        if (gy >= 0 && gy < HH && gx >= 0 && gx < WW)
            v = *(const float4*)(xb + (size_t)(gy * WW + gx) * CC + cq * 4);
        *(uint2*)(xt + p * XSTR + cq * 4) = make_uint2(packtr(v.x, v.y), packtr(v.z, v.w));
        if (cq == 0) at[p] = v.w;   // channel 3
    }
    __syncthreads();

    // ---- pre_life: 3x3 max of alpha > 0.1 ----
    {
        float m = -1.f;
        #pragma unroll
        for (int dy = 0; dy < 3; ++dy) {
            const float* r = at + (ty + dy) * 18 + tx;
            m = fmaxf(m, fmaxf(fmaxf(r[0], r[1]), r[2]));
        }
        const size_t pix0 = (size_t)b * HH * WW + (size_t)(by + ty) * WW + (bx + tx);
        pre_out[pix0] = (m > 0.1f) ? 1.f : 0.f;
    }

    // ---- MFMA phase: wave w owns pixels [64w, 64w+64), 4 nt-tiles of 16 ----
    const int w = tid >> 6, lane = tid & 63;
    const int quad = lane >> 4, lr = lane & 15;
    const int qh = quad >> 1, c0 = (quad & 1) * 8;

    // per-lane tap offsets (bf16 units) for ks=0..4: t = 2ks + qh (clamped to 8)
    // off(t) = ((t/3)*18 + t%3) * XSTR
    const int off0 = qh ? (1 * XSTR) : 0;
    const int off1 = qh ? (18 * XSTR + 0 * XSTR) : (2 * XSTR);
    const int off2 = qh ? (18 * XSTR + 2 * XSTR) : (18 * XSTR + 1 * XSTR);
    const int off3 = qh ? (36 * XSTR + 1 * XSTR) : (36 * XSTR + 0 * XSTR);
    const int off4 = 36 * XSTR + 2 * XSTR;   // t=8 both (qh=1 side has zero weights)

    floatx4 dacc[4] = {{0.f,0.f,0.f,0.f},{0.f,0.f,0.f,0.f},
                       {0.f,0.f,0.f,0.f},{0.f,0.f,0.f,0.f}};

    unsigned short* Hw = &Hb[w][0];

    #pragma unroll 1
    for (int q = 0; q < 4; ++q) {
        // A-frags for this hid-quarter: 2 m-tiles x 5 k-steps (40 VGPRs)
        short8 A0[2][5];
        #pragma unroll
        for (int mt = 0; mt < 2; ++mt)
            #pragma unroll
            for (int ks = 0; ks < 5; ++ks)
                A0[mt][ks] = *(const short8*)(w0e + (q * 32 + mt * 16 + lr) * KEXP
                                              + ks * 32 + quad * 8);
        const short8 A1q = *(const short8*)(w1b + lr * HID + q * 32 + quad * 8);

        // Bf double-buffer: [nt&1] = current, [(nt&1)^1] = prefetch target.
        short8 Bf[2][5];
        {
            const int base0 = ((w * 4 + 0) * 18 + lr) * XSTR + c0;
            Bf[0][0] = *(const short8*)(xt + base0 + off0);
            Bf[0][1] = *(const short8*)(xt + base0 + off1);
            Bf[0][2] = *(const short8*)(xt + base0 + off2);
            Bf[0][3] = *(const short8*)(xt + base0 + off3);
            Bf[0][4] = *(const short8*)(xt + base0 + off4);
        }

        #pragma unroll
        for (int nt = 0; nt < 4; ++nt) {
            const int cur = nt & 1, nxt = cur ^ 1;

            #pragma unroll
            for (int mt = 0; mt < 2; ++mt) {
                floatx4 acc = {0.f, 0.f, 0.f, 0.f};
                acc = __builtin_amdgcn_mfma_f32_16x16x32_bf16(A0[mt][0], Bf[cur][0], acc, 0, 0, 0);
                acc = __builtin_amdgcn_mfma_f32_16x16x32_bf16(A0[mt][1], Bf[cur][1], acc, 0, 0, 0);
                acc = __builtin_amdgcn_mfma_f32_16x16x32_bf16(A0[mt][2], Bf[cur][2], acc, 0, 0, 0);
                acc = __builtin_amdgcn_mfma_f32_16x16x32_bf16(A0[mt][3], Bf[cur][3], acc, 0, 0, 0);
                acc = __builtin_amdgcn_mfma_f32_16x16x32_bf16(A0[mt][4], Bf[cur][4], acc, 0, 0, 0);
                // lane holds H[pixel=lr][hid = q*32 + mt*16 + quad*4 + r]
                unsigned int lo = packtr(fmaxf(acc[0], 0.f), fmaxf(acc[1], 0.f));
                unsigned int hi = packtr(fmaxf(acc[2], 0.f), fmaxf(acc[3], 0.f));
                *(uint2*)(Hw + lr * HSTR + mt * 16 + quad * 4) = make_uint2(lo, hi);
            }
            // Bh read issued after both H-writes (may-alias => compiler keeps
            // order; in-order LDS => counted wait on Bh implies writes landed).
            short8 Bh = *(const short8*)(Hw + lr * HSTR + quad * 8);

            // prefetch next nt's B-frags; their lgkmcnt stays outstanding
            // across GEMM2 below (compiler waits lgkmcnt(5) for Bh only).
            if (nt < 3) {
                const int basen = ((w * 4 + nt + 1) * 18 + lr) * XSTR + c0;
                Bf[nxt][0] = *(const short8*)(xt + basen + off0);
                Bf[nxt][1] = *(const short8*)(xt + basen + off1);
                Bf[nxt][2] = *(const short8*)(xt + basen + off2);
                Bf[nxt][3] = *(const short8*)(xt + basen + off3);
                Bf[nxt][4] = *(const short8*)(xt + basen + off4);
            }

            dacc[nt] = __builtin_amdgcn_mfma_f32_16x16x32_bf16(A1q, Bh, dacc[nt], 0, 0, 0);
        }
    }

    // ---- epilogue: lane holds dx[pixel = w*64+nt*16+lr][o = quad*4+r] ----
    #pragma unroll
    for (int nt = 0; nt < 4; ++nt) {
        const int gy = by + w * 4 + nt, gx = bx + lr;
        const size_t pix = (size_t)b * HH * WW + (size_t)gy * WW + gx;
        const float upd = (rand_mask[pix] <= 0.5f) ? 1.f : 0.f;
        const float4 xc = *(const float4*)(x + pix * CC + quad * 4);
        float4 xn;
        xn.x = xc.x + dacc[nt][0] * upd;
        xn.y = xc.y + dacc[nt][1] * upd;
        xn.z = xc.z + dacc[nt][2] * upd;
        xn.w = xc.w + dacc[nt][3] * upd;
        *(float4*)(xn_out + pix * CC + quad * 4) = xn;
        if (quad == 0) alpha_out[pix] = xn.w;   // channel 3
    }
}

// ---------------------------------------------------------------------------
// pass2: out already holds xn; zero only dead pixels (life==0).
// 4 px/thread, 64x16 tile, float4 alpha/pre loads -> 1024 blocks.
// ---------------------------------------------------------------------------
#define P2W 64
#define P2H 16
__global__ __launch_bounds__(256)
void pass2(const float* __restrict__ alpha, const float* __restrict__ pre,
           float* __restrict__ out)
{
    __shared__ float at2[18][66];
    const int tx = threadIdx.x, ty = threadIdx.y;   // 16 x 16
    const int bx = blockIdx.x * P2W, by = blockIdx.y * P2H, b = blockIdx.z;
    const int tid = ty * 16 + tx;
    const float* ab = alpha + (size_t)b * HH * WW;

    // interior: 18 rows x 16 float4 segs (cols bx..bx+63 -> at2 cols 1..64)
    for (int idx = tid; idx < 18 * 16; idx += 256) {
        int r = idx >> 4, s = idx & 15;
        int gy = by + r - 1;
        float4 v = make_float4(0.f, 0.f, 0.f, 0.f);
        if (gy >= 0 && gy < HH)
            v = *(const float4*)(ab + (size_t)gy * WW + (bx + s * 4));
        at2[r][1 + s * 4 + 0] = v.x;
        at2[r][1 + s * 4 + 1] = v.y;
        at2[r][1 + s * 4 + 2] = v.z;
        at2[r][1 + s * 4 + 3] = v.w;
    }
    // halo edges: 18 rows x 2 cols
    if (tid < 36) {
        int r = tid >> 1, e = tid & 1;
        int gy = by + r - 1, gx = e ? (bx + P2W) : (bx - 1);
        float v = 0.f;
        if (gy >= 0 && gy < HH && gx >= 0 && gx < WW) v = ab[(size_t)gy * WW + gx];
        at2[r][e ? 65 : 0] = v;
    }
    __syncthreads();

    const int x0 = tx * 4;
    float vm0 = -1.f, vm1 = -1.f, vm2 = -1.f, vm3 = -1.f;
    #pragma unroll
    for (int dr = 0; dr < 3; ++dr) {
        const float* rp = &at2[ty + dr][x0];   // col x0 == gx (bx+x0-1)
        float a0 = rp[0], a1 = rp[1], a2 = rp[2];
        float a3 = rp[3], a4 = rp[4], a5 = rp[5];
        vm0 = fmaxf(vm0, fmaxf(fmaxf(a0, a1), a2));
        vm1 = fmaxf(vm1, fmaxf(fmaxf(a1, a2), a3));
        vm2 = fmaxf(vm2, fmaxf(fmaxf(a2, a3), a4));
        vm3 = fmaxf(vm3, fmaxf(fmaxf(a3, a4), a5));
    }

    const size_t pix0 = (size_t)b * HH * WW + (size_t)(by + ty) * WW + (bx + x0);
    const float4 pr = *(const float4*)(pre + pix0);
    const float vms[4] = {vm0, vm1, vm2, vm3};
    const float prs[4] = {pr.x, pr.y, pr.z, pr.w};
    #pragma unroll
    for (int j = 0; j < 4; ++j) {
        if (!(vms[j] > 0.1f && prs[j] > 0.5f)) {
            float4 z = make_float4(0.f, 0.f, 0.f, 0.f);
            float4* o4 = (float4*)(out + (pix0 + j) * CC);
            o4[0] = z; o4[1] = z; o4[2] = z; o4[3] = z;
        }
    }
}

extern "C" void kernel_launch(void* const* d_in, const int* in_sizes, int n_in,
                              void* d_out, int out_size, void* d_ws, size_t ws_size,
                              hipStream_t stream) {
    const float* x  = (const float*)d_in[0];
    const float* w0 = (const float*)d_in[1];
    const float* w1 = (const float*)d_in[2];
    const float* rm = (const float*)d_in[3];
    float* out = (float*)d_out;

    float* ws    = (float*)d_ws;
    float* alpha = ws;                         // B*H*W floats
    float* pre   = ws + NPIX;                  // B*H*W floats
    unsigned short* w0e = (unsigned short*)(ws + 2 * NPIX);  // 128*160 bf16
    unsigned short* w1b = w0e + HID * KEXP;                  // 16*128 bf16

    prep<<<(HID * KEXP + 255) / 256, 256, 0, stream>>>(w0, w1, w0e, w1b);

    dim3 grid(WW / TS, HH / TS, BB);
    dim3 blk(TS, TS);
    pass1<<<grid, blk, 0, stream>>>(x, w0e, w1b, rm, out, alpha, pre);

    dim3 grid2(WW / P2W, HH / P2H, BB);
    pass2<<<grid2, dim3(16, 16), 0, stream>>>(alpha, pre, out);
}

// Round 5
// 187.831 us; speedup vs baseline: 1.5700x; 1.1275x over previous
//
#include <hip/hip_runtime.h>

#define BB 16
#define HH 256
#define WW 256
#define CC 16
#define HID 128
#define TS 16
#define NPIX ((size_t)BB * HH * WW)
#define KEXP 160   // 9 taps x 16 ch = 144, padded to 160 (tap 9 = zero weights)
#define XSTR 24    // xt pixel stride in bf16 (48 B: 16B-aligned; 2-way bank alias = free)
#define HSTR 40    // H row stride in bf16 (80 B: 16B-aligned; 10-dword stride -> 16 distinct banks)

typedef __attribute__((ext_vector_type(8))) short short8;
typedef __attribute__((ext_vector_type(4))) float floatx4;

__device__ inline unsigned int f2bf(float f) {
    unsigned int u = __float_as_uint(f);
    return (u + 0x7FFFu + ((u >> 16) & 1u)) >> 16;   // RNE (prep only)
}
// truncating bf16x2 pack: one v_perm_b32. mem order: lo then hi.
__device__ inline unsigned int packtr(float lo, float hi) {
    return __builtin_amdgcn_perm(__float_as_uint(hi), __float_as_uint(lo), 0x07060302u);
}

// ---------------------------------------------------------------------------
// prep: w0e[n][t*16+c] = sobel-folded first-layer weights (128 x 160 bf16,
// cols 144..159 zero). w1b[o][c_hid] = 16 x 128 bf16.
// ---------------------------------------------------------------------------
__global__ void prep(const float* __restrict__ w0, const float* __restrict__ w1,
                     unsigned short* __restrict__ w0e, unsigned short* __restrict__ w1b) {
    int i = blockIdx.x * blockDim.x + threadIdx.x;
    if (i < HID * KEXP) {
        int n = i / KEXP, k = i % KEXP;
        int t = k >> 4, c = k & 15;
        float v = 0.f;
        if (t < 9) {
            int dy = t / 3, dx = t % 3;
            float id = (t == 4) ? 1.f : 0.f;
            float sx = (float)(dx - 1) * ((dy == 1) ? 2.f : 1.f) * 0.125f;
            float sy = (float)(dy - 1) * ((dx == 1) ? 2.f : 1.f) * 0.125f;
            v = w0[n * 48 + 3 * c] * id + w0[n * 48 + 3 * c + 1] * sx
              + w0[n * 48 + 3 * c + 2] * sy;
        }
        w0e[i] = (unsigned short)f2bf(v);
    }
    if (i < CC * HID) w1b[i] = (unsigned short)f2bf(w1[i]);
}

// ---------------------------------------------------------------------------
// pass1: EXACT r0 structure/schedule (VGPR=60, the only config that hit 97us)
// with ONE isolated change: Hb single-buffered instead of ping-pong.
//   - Correctness proven in r2/r3/r4 (all passed): the per-iteration
//     lgkmcnt(0) drain retires iter i's reads before iter i+1's writes,
//     and same-wave DS ops complete in order.
//   - LDS 27136 -> 22016 B => 7 blocks/CU (r0: 6). Occupancy is the only
//     lever that has correlated with pass1 time (r0/r1/r4 3-point curve);
//     this raises it with ZERO VGPR cost.
// Do NOT: cap launch_bounds (r2: spill disaster), odd strides (r3: splits
// b128), Bf double-buffer (r4: +32 VGPR -> occupancy loss > ILP gain).
// C/D layout: col=lane&15, row=quad*4+reg (m89/m91-verified)
// ---------------------------------------------------------------------------
__global__ __launch_bounds__(256)
void pass1(const float* __restrict__ x, const unsigned short* __restrict__ w0e,
           const unsigned short* __restrict__ w1b, const float* __restrict__ rand_mask,
           float* __restrict__ xn_out, float* __restrict__ alpha_out,
           float* __restrict__ pre_out)
{
    __shared__ unsigned short xt[18 * 18 * XSTR];          // bf16 halo tile
    __shared__ float at[18 * 18];                          // alpha (ch3) fp32 plane
    __shared__ unsigned short Hb[4][16 * HSTR];            // per-wave H buffer (single)

    const int tx = threadIdx.x, ty = threadIdx.y;
    const int bx = blockIdx.x * TS, by = blockIdx.y * TS, b = blockIdx.z;
    const int tid = ty * TS + tx;
    const float* xb = x + (size_t)b * HH * WW * CC;

    // ---- stage halo tile: fp32 global -> bf16 LDS (+ alpha plane) ----
    for (int idx = tid; idx < 18 * 18 * 4; idx += 256) {
        int cq = idx & 3, p = idx >> 2;
        int lyy = p / 18, lxx = p % 18;
        int gy = by + lyy - 1, gx = bx + lxx - 1;
        float4 v = make_float4(0.f, 0.f, 0.f, 0.f);
        if (gy >= 0 && gy < HH && gx >= 0 && gx < WW)
            v = *(const float4*)(xb + (size_t)(gy * WW + gx) * CC + cq * 4);
        *(uint2*)(xt + p * XSTR + cq * 4) = make_uint2(packtr(v.x, v.y), packtr(v.z, v.w));
        if (cq == 0) at[p] = v.w;   // channel 3
    }
    __syncthreads();

    // ---- pre_life: 3x3 max of alpha > 0.1 ----
    {
        float m = -1.f;
        #pragma unroll
        for (int dy = 0; dy < 3; ++dy) {
            const float* r = at + (ty + dy) * 18 + tx;
            m = fmaxf(m, fmaxf(fmaxf(r[0], r[1]), r[2]));
        }
        const size_t pix0 = (size_t)b * HH * WW + (size_t)(by + ty) * WW + (bx + tx);
        pre_out[pix0] = (m > 0.1f) ? 1.f : 0.f;
    }

    // ---- MFMA phase: wave w owns pixels [64w, 64w+64), 4 nt-tiles of 16 ----
    const int w = tid >> 6, lane = tid & 63;
    const int quad = lane >> 4, lr = lane & 15;
    const int qh = quad >> 1, c0 = (quad & 1) * 8;

    // per-lane tap offsets (bf16 units) for ks=0..4: t = 2ks + qh (clamped to 8)
    // off(t) = ((t/3)*18 + t%3) * XSTR
    const int off0 = qh ? (1 * XSTR) : 0;
    const int off1 = qh ? (18 * XSTR + 0 * XSTR) : (2 * XSTR);
    const int off2 = qh ? (18 * XSTR + 2 * XSTR) : (18 * XSTR + 1 * XSTR);
    const int off3 = qh ? (36 * XSTR + 1 * XSTR) : (36 * XSTR + 0 * XSTR);
    const int off4 = 36 * XSTR + 2 * XSTR;   // t=8 both (qh=1 side has zero weights)

    floatx4 dacc[4] = {{0.f,0.f,0.f,0.f},{0.f,0.f,0.f,0.f},
                       {0.f,0.f,0.f,0.f},{0.f,0.f,0.f,0.f}};

    unsigned short* Hw = &Hb[w][0];

    #pragma unroll 1
    for (int q = 0; q < 4; ++q) {
        // A-frags for this hid-quarter: 2 m-tiles x 5 k-steps (40 VGPRs)
        short8 A0[2][5];
        #pragma unroll
        for (int mt = 0; mt < 2; ++mt)
            #pragma unroll
            for (int ks = 0; ks < 5; ++ks)
                A0[mt][ks] = *(const short8*)(w0e + (q * 32 + mt * 16 + lr) * KEXP
                                              + ks * 32 + quad * 8);
        const short8 A1q = *(const short8*)(w1b + lr * HID + q * 32 + quad * 8);

        #pragma unroll
        for (int nt = 0; nt < 4; ++nt) {
            const int base = ((w * 4 + nt) * 18 + lr) * XSTR + c0;
            short8 Bf0 = *(const short8*)(xt + base + off0);
            short8 Bf1 = *(const short8*)(xt + base + off1);
            short8 Bf2 = *(const short8*)(xt + base + off2);
            short8 Bf3 = *(const short8*)(xt + base + off3);
            short8 Bf4 = *(const short8*)(xt + base + off4);

            #pragma unroll
            for (int mt = 0; mt < 2; ++mt) {
                floatx4 acc = {0.f, 0.f, 0.f, 0.f};
                acc = __builtin_amdgcn_mfma_f32_16x16x32_bf16(A0[mt][0], Bf0, acc, 0, 0, 0);
                acc = __builtin_amdgcn_mfma_f32_16x16x32_bf16(A0[mt][1], Bf1, acc, 0, 0, 0);
                acc = __builtin_amdgcn_mfma_f32_16x16x32_bf16(A0[mt][2], Bf2, acc, 0, 0, 0);
                acc = __builtin_amdgcn_mfma_f32_16x16x32_bf16(A0[mt][3], Bf3, acc, 0, 0, 0);
                acc = __builtin_amdgcn_mfma_f32_16x16x32_bf16(A0[mt][4], Bf4, acc, 0, 0, 0);
                // lane holds H[pixel=lr][hid = q*32 + mt*16 + quad*4 + r]
                unsigned int lo = packtr(fmaxf(acc[0], 0.f), fmaxf(acc[1], 0.f));
                unsigned int hi = packtr(fmaxf(acc[2], 0.f), fmaxf(acc[3], 0.f));
                *(uint2*)(Hw + lr * HSTR + mt * 16 + quad * 4) = make_uint2(lo, hi);
            }
            // RAW: cross-lane H writes must land before B-read (also retires
            // this iteration's reads -> next iteration's writes are WAR-safe
            // on the single buffer)
            asm volatile("s_waitcnt lgkmcnt(0)" ::: "memory");
            short8 Bh = *(const short8*)(Hw + lr * HSTR + quad * 8);
            dacc[nt] = __builtin_amdgcn_mfma_f32_16x16x32_bf16(A1q, Bh, dacc[nt], 0, 0, 0);
        }
    }

    // ---- epilogue: lane holds dx[pixel = w*64+nt*16+lr][o = quad*4+r] ----
    #pragma unroll
    for (int nt = 0; nt < 4; ++nt) {
        const int gy = by + w * 4 + nt, gx = bx + lr;
        const size_t pix = (size_t)b * HH * WW + (size_t)gy * WW + gx;
        const float upd = (rand_mask[pix] <= 0.5f) ? 1.f : 0.f;
        const float4 xc = *(const float4*)(x + pix * CC + quad * 4);
        float4 xn;
        xn.x = xc.x + dacc[nt][0] * upd;
        xn.y = xc.y + dacc[nt][1] * upd;
        xn.z = xc.z + dacc[nt][2] * upd;
        xn.w = xc.w + dacc[nt][3] * upd;
        *(float4*)(xn_out + pix * CC + quad * 4) = xn;
        if (quad == 0) alpha_out[pix] = xn.w;   // channel 3
    }
}

// ---------------------------------------------------------------------------
// pass2: out already holds xn; zero only dead pixels (life==0).
// 4 px/thread, 64x16 tile, float4 alpha/pre loads -> 1024 blocks.
// ---------------------------------------------------------------------------
#define P2W 64
#define P2H 16
__global__ __launch_bounds__(256)
void pass2(const float* __restrict__ alpha, const float* __restrict__ pre,
           float* __restrict__ out)
{
    __shared__ float at2[18][66];
    const int tx = threadIdx.x, ty = threadIdx.y;   // 16 x 16
    const int bx = blockIdx.x * P2W, by = blockIdx.y * P2H, b = blockIdx.z;
    const int tid = ty * 16 + tx;
    const float* ab = alpha + (size_t)b * HH * WW;

    // interior: 18 rows x 16 float4 segs (cols bx..bx+63 -> at2 cols 1..64)
    for (int idx = tid; idx < 18 * 16; idx += 256) {
        int r = idx >> 4, s = idx & 15;
        int gy = by + r - 1;
        float4 v = make_float4(0.f, 0.f, 0.f, 0.f);
        if (gy >= 0 && gy < HH)
            v = *(const float4*)(ab + (size_t)gy * WW + (bx + s * 4));
        at2[r][1 + s * 4 + 0] = v.x;
        at2[r][1 + s * 4 + 1] = v.y;
        at2[r][1 + s * 4 + 2] = v.z;
        at2[r][1 + s * 4 + 3] = v.w;
    }
    // halo edges: 18 rows x 2 cols
    if (tid < 36) {
        int r = tid >> 1, e = tid & 1;
        int gy = by + r - 1, gx = e ? (bx + P2W) : (bx - 1);
        float v = 0.f;
        if (gy >= 0 && gy < HH && gx >= 0 && gx < WW) v = ab[(size_t)gy * WW + gx];
        at2[r][e ? 65 : 0] = v;
    }
    __syncthreads();

    const int x0 = tx * 4;
    float vm0 = -1.f, vm1 = -1.f, vm2 = -1.f, vm3 = -1.f;
    #pragma unroll
    for (int dr = 0; dr < 3; ++dr) {
        const float* rp = &at2[ty + dr][x0];   // col x0 == gx (bx+x0-1)
        float a0 = rp[0], a1 = rp[1], a2 = rp[2];
        float a3 = rp[3], a4 = rp[4], a5 = rp[5];
        vm0 = fmaxf(vm0, fmaxf(fmaxf(a0, a1), a2));
        vm1 = fmaxf(vm1, fmaxf(fmaxf(a1, a2), a3));
        vm2 = fmaxf(vm2, fmaxf(fmaxf(a2, a3), a4));
        vm3 = fmaxf(vm3, fmaxf(fmaxf(a3, a4), a5));
    }

    const size_t pix0 = (size_t)b * HH * WW + (size_t)(by + ty) * WW + (bx + x0);
    const float4 pr = *(const float4*)(pre + pix0);
    const float vms[4] = {vm0, vm1, vm2, vm3};
    const float prs[4] = {pr.x, pr.y, pr.z, pr.w};
    #pragma unroll
    for (int j = 0; j < 4; ++j) {
        if (!(vms[j] > 0.1f && prs[j] > 0.5f)) {
            float4 z = make_float4(0.f, 0.f, 0.f, 0.f);
            float4* o4 = (float4*)(out + (pix0 + j) * CC);
            o4[0] = z; o4[1] = z; o4[2] = z; o4[3] = z;
        }
    }
}

extern "C" void kernel_launch(void* const* d_in, const int* in_sizes, int n_in,
                              void* d_out, int out_size, void* d_ws, size_t ws_size,
                              hipStream_t stream) {
    const float* x  = (const float*)d_in[0];
    const float* w0 = (const float*)d_in[1];
    const float* w1 = (const float*)d_in[2];
    const float* rm = (const float*)d_in[3];
    float* out = (float*)d_out;

    float* ws    = (float*)d_ws;
    float* alpha = ws;                         // B*H*W floats
    float* pre   = ws + NPIX;                  // B*H*W floats
    unsigned short* w0e = (unsigned short*)(ws + 2 * NPIX);  // 128*160 bf16
    unsigned short* w1b = w0e + HID * KEXP;                  // 16*128 bf16

    prep<<<(HID * KEXP + 255) / 256, 256, 0, stream>>>(w0, w1, w0e, w1b);

    dim3 grid(WW / TS, HH / TS, BB);
    dim3 blk(TS, TS);
    pass1<<<grid, blk, 0, stream>>>(x, w0e, w1b, rm, out, alpha, pre);

    dim3 grid2(WW / P2W, HH / P2H, BB);
    pass2<<<grid2, dim3(16, 16), 0, stream>>>(alpha, pre, out);
}

// Round 6
// 184.801 us; speedup vs baseline: 1.5957x; 1.0164x over previous
//
#include <hip/hip_runtime.h>

#define BB 16
#define HH 256
#define WW 256
#define CC 16
#define HID 128
#define TS 16
#define NPIX ((size_t)BB * HH * WW)
#define KEXP 160   // 9 taps x 16 ch = 144, padded to 160 (tap 9 = zero weights)
#define XSTR 24    // xt pixel stride in bf16 (48 B: 16B-aligned; 2-way bank alias = free)
#define HSTR 40    // H row stride in bf16 (80 B: 16B-aligned)

typedef __attribute__((ext_vector_type(8))) short short8;
typedef __attribute__((ext_vector_type(4))) float floatx4;

__device__ inline unsigned int f2bf(float f) {
    unsigned int u = __float_as_uint(f);
    return (u + 0x7FFFu + ((u >> 16) & 1u)) >> 16;   // RNE (prep only)
}
// truncating bf16x2 pack: one v_perm_b32. mem order: lo then hi.
__device__ inline unsigned int packtr(float lo, float hi) {
    return __builtin_amdgcn_perm(__float_as_uint(hi), __float_as_uint(lo), 0x07060302u);
}

// ---------------------------------------------------------------------------
// prep: w0e[n][t*16+c] = sobel-folded first-layer weights (128 x 160 bf16,
// cols 144..159 zero). w1b[o][c_hid] = 16 x 128 bf16.
// ---------------------------------------------------------------------------
__global__ void prep(const float* __restrict__ w0, const float* __restrict__ w1,
                     unsigned short* __restrict__ w0e, unsigned short* __restrict__ w1b) {
    int i = blockIdx.x * blockDim.x + threadIdx.x;
    if (i < HID * KEXP) {
        int n = i / KEXP, k = i % KEXP;
        int t = k >> 4, c = k & 15;
        float v = 0.f;
        if (t < 9) {
            int dy = t / 3, dx = t % 3;
            float id = (t == 4) ? 1.f : 0.f;
            float sx = (float)(dx - 1) * ((dy == 1) ? 2.f : 1.f) * 0.125f;
            float sy = (float)(dy - 1) * ((dx == 1) ? 2.f : 1.f) * 0.125f;
            v = w0[n * 48 + 3 * c] * id + w0[n * 48 + 3 * c + 1] * sx
              + w0[n * 48 + 3 * c + 2] * sy;
        }
        w0e[i] = (unsigned short)f2bf(v);
    }
    if (i < CC * HID) w1b[i] = (unsigned short)f2bf(w1[i]);
}

// ---------------------------------------------------------------------------
// pass1: EXACT r5 structure/schedule with ONE isolated change:
// __launch_bounds__(256, 4) — total-register budget 512/4 = 128 (arch+accum,
// gfx950 unified file).
// WHY: occupancy tracks registers across r0-r5 (36reg->68%, 60->38%, 88->21%,
// 92->20%) while LDS 22-27KB had ZERO effect (r5 isolation). True footprint
// ~150 total (60 arch + ~90 accum) -> 3 waves/SIMD. Budget 128 needs only
// ~22 regs of rematerialization (r2's disaster was budget 73 vs need 150).
// SUCCESS CRITERION: FETCH ~65MB / WRITE ~74MB unchanged (no spill),
// occupancy -> ~50%. If FETCH/WRITE jump: spilled, revert.
// C/D layout: col=lane&15, row=quad*4+reg (m89/m91-verified)
// ---------------------------------------------------------------------------
__global__ __launch_bounds__(256, 4)
void pass1(const float* __restrict__ x, const unsigned short* __restrict__ w0e,
           const unsigned short* __restrict__ w1b, const float* __restrict__ rand_mask,
           float* __restrict__ xn_out, float* __restrict__ alpha_out,
           float* __restrict__ pre_out)
{
    __shared__ unsigned short xt[18 * 18 * XSTR];          // bf16 halo tile
    __shared__ float at[18 * 18];                          // alpha (ch3) fp32 plane
    __shared__ unsigned short Hb[4][16 * HSTR];            // per-wave H buffer (single)

    const int tx = threadIdx.x, ty = threadIdx.y;
    const int bx = blockIdx.x * TS, by = blockIdx.y * TS, b = blockIdx.z;
    const int tid = ty * TS + tx;
    const float* xb = x + (size_t)b * HH * WW * CC;

    // ---- stage halo tile: fp32 global -> bf16 LDS (+ alpha plane) ----
    for (int idx = tid; idx < 18 * 18 * 4; idx += 256) {
        int cq = idx & 3, p = idx >> 2;
        int lyy = p / 18, lxx = p % 18;
        int gy = by + lyy - 1, gx = bx + lxx - 1;
        float4 v = make_float4(0.f, 0.f, 0.f, 0.f);
        if (gy >= 0 && gy < HH && gx >= 0 && gx < WW)
            v = *(const float4*)(xb + (size_t)(gy * WW + gx) * CC + cq * 4);
        *(uint2*)(xt + p * XSTR + cq * 4) = make_uint2(packtr(v.x, v.y), packtr(v.z, v.w));
        if (cq == 0) at[p] = v.w;   // channel 3
    }
    __syncthreads();

    // ---- pre_life: 3x3 max of alpha > 0.1 ----
    {
        float m = -1.f;
        #pragma unroll
        for (int dy = 0; dy < 3; ++dy) {
            const float* r = at + (ty + dy) * 18 + tx;
            m = fmaxf(m, fmaxf(fmaxf(r[0], r[1]), r[2]));
        }
        const size_t pix0 = (size_t)b * HH * WW + (size_t)(by + ty) * WW + (bx + tx);
        pre_out[pix0] = (m > 0.1f) ? 1.f : 0.f;
    }

    // ---- MFMA phase: wave w owns pixels [64w, 64w+64), 4 nt-tiles of 16 ----
    const int w = tid >> 6, lane = tid & 63;
    const int quad = lane >> 4, lr = lane & 15;
    const int qh = quad >> 1, c0 = (quad & 1) * 8;

    // per-lane tap offsets (bf16 units) for ks=0..4: t = 2ks + qh (clamped to 8)
    // off(t) = ((t/3)*18 + t%3) * XSTR
    const int off0 = qh ? (1 * XSTR) : 0;
    const int off1 = qh ? (18 * XSTR + 0 * XSTR) : (2 * XSTR);
    const int off2 = qh ? (18 * XSTR + 2 * XSTR) : (18 * XSTR + 1 * XSTR);
    const int off3 = qh ? (36 * XSTR + 1 * XSTR) : (36 * XSTR + 0 * XSTR);
    const int off4 = 36 * XSTR + 2 * XSTR;   // t=8 both (qh=1 side has zero weights)

    floatx4 dacc[4] = {{0.f,0.f,0.f,0.f},{0.f,0.f,0.f,0.f},
                       {0.f,0.f,0.f,0.f},{0.f,0.f,0.f,0.f}};

    unsigned short* Hw = &Hb[w][0];

    #pragma unroll 1
    for (int q = 0; q < 4; ++q) {
        // A-frags for this hid-quarter: 2 m-tiles x 5 k-steps (40 VGPRs)
        short8 A0[2][5];
        #pragma unroll
        for (int mt = 0; mt < 2; ++mt)
            #pragma unroll
            for (int ks = 0; ks < 5; ++ks)
                A0[mt][ks] = *(const short8*)(w0e + (q * 32 + mt * 16 + lr) * KEXP
                                              + ks * 32 + quad * 8);
        const short8 A1q = *(const short8*)(w1b + lr * HID + q * 32 + quad * 8);

        #pragma unroll
        for (int nt = 0; nt < 4; ++nt) {
            const int base = ((w * 4 + nt) * 18 + lr) * XSTR + c0;
            short8 Bf0 = *(const short8*)(xt + base + off0);
            short8 Bf1 = *(const short8*)(xt + base + off1);
            short8 Bf2 = *(const short8*)(xt + base + off2);
            short8 Bf3 = *(const short8*)(xt + base + off3);
            short8 Bf4 = *(const short8*)(xt + base + off4);

            #pragma unroll
            for (int mt = 0; mt < 2; ++mt) {
                floatx4 acc = {0.f, 0.f, 0.f, 0.f};
                acc = __builtin_amdgcn_mfma_f32_16x16x32_bf16(A0[mt][0], Bf0, acc, 0, 0, 0);
                acc = __builtin_amdgcn_mfma_f32_16x16x32_bf16(A0[mt][1], Bf1, acc, 0, 0, 0);
                acc = __builtin_amdgcn_mfma_f32_16x16x32_bf16(A0[mt][2], Bf2, acc, 0, 0, 0);
                acc = __builtin_amdgcn_mfma_f32_16x16x32_bf16(A0[mt][3], Bf3, acc, 0, 0, 0);
                acc = __builtin_amdgcn_mfma_f32_16x16x32_bf16(A0[mt][4], Bf4, acc, 0, 0, 0);
                // lane holds H[pixel=lr][hid = q*32 + mt*16 + quad*4 + r]
                unsigned int lo = packtr(fmaxf(acc[0], 0.f), fmaxf(acc[1], 0.f));
                unsigned int hi = packtr(fmaxf(acc[2], 0.f), fmaxf(acc[3], 0.f));
                *(uint2*)(Hw + lr * HSTR + mt * 16 + quad * 4) = make_uint2(lo, hi);
            }
            // RAW: cross-lane H writes must land before B-read (also retires
            // this iteration's reads -> next iteration's writes are WAR-safe
            // on the single buffer)
            asm volatile("s_waitcnt lgkmcnt(0)" ::: "memory");
            short8 Bh = *(const short8*)(Hw + lr * HSTR + quad * 8);
            dacc[nt] = __builtin_amdgcn_mfma_f32_16x16x32_bf16(A1q, Bh, dacc[nt], 0, 0, 0);
        }
    }

    // ---- epilogue: lane holds dx[pixel = w*64+nt*16+lr][o = quad*4+r] ----
    #pragma unroll
    for (int nt = 0; nt < 4; ++nt) {
        const int gy = by + w * 4 + nt, gx = bx + lr;
        const size_t pix = (size_t)b * HH * WW + (size_t)gy * WW + gx;
        const float upd = (rand_mask[pix] <= 0.5f) ? 1.f : 0.f;
        const float4 xc = *(const float4*)(x + pix * CC + quad * 4);
        float4 xn;
        xn.x = xc.x + dacc[nt][0] * upd;
        xn.y = xc.y + dacc[nt][1] * upd;
        xn.z = xc.z + dacc[nt][2] * upd;
        xn.w = xc.w + dacc[nt][3] * upd;
        *(float4*)(xn_out + pix * CC + quad * 4) = xn;
        if (quad == 0) alpha_out[pix] = xn.w;   // channel 3
    }
}

// ---------------------------------------------------------------------------
// pass2: out already holds xn; zero only dead pixels (life==0).
// 4 px/thread, 64x16 tile, float4 alpha/pre loads -> 1024 blocks.
// ---------------------------------------------------------------------------
#define P2W 64
#define P2H 16
__global__ __launch_bounds__(256)
void pass2(const float* __restrict__ alpha, const float* __restrict__ pre,
           float* __restrict__ out)
{
    __shared__ float at2[18][66];
    const int tx = threadIdx.x, ty = threadIdx.y;   // 16 x 16
    const int bx = blockIdx.x * P2W, by = blockIdx.y * P2H, b = blockIdx.z;
    const int tid = ty * 16 + tx;
    const float* ab = alpha + (size_t)b * HH * WW;

    // interior: 18 rows x 16 float4 segs (cols bx..bx+63 -> at2 cols 1..64)
    for (int idx = tid; idx < 18 * 16; idx += 256) {
        int r = idx >> 4, s = idx & 15;
        int gy = by + r - 1;
        float4 v = make_float4(0.f, 0.f, 0.f, 0.f);
        if (gy >= 0 && gy < HH)
            v = *(const float4*)(ab + (size_t)gy * WW + (bx + s * 4));
        at2[r][1 + s * 4 + 0] = v.x;
        at2[r][1 + s * 4 + 1] = v.y;
        at2[r][1 + s * 4 + 2] = v.z;
        at2[r][1 + s * 4 + 3] = v.w;
    }
    // halo edges: 18 rows x 2 cols
    if (tid < 36) {
        int r = tid >> 1, e = tid & 1;
        int gy = by + r - 1, gx = e ? (bx + P2W) : (bx - 1);
        float v = 0.f;
        if (gy >= 0 && gy < HH && gx >= 0 && gx < WW) v = ab[(size_t)gy * WW + gx];
        at2[r][e ? 65 : 0] = v;
    }
    __syncthreads();

    const int x0 = tx * 4;
    float vm0 = -1.f, vm1 = -1.f, vm2 = -1.f, vm3 = -1.f;
    #pragma unroll
    for (int dr = 0; dr < 3; ++dr) {
        const float* rp = &at2[ty + dr][x0];   // col x0 == gx (bx+x0-1)
        float a0 = rp[0], a1 = rp[1], a2 = rp[2];
        float a3 = rp[3], a4 = rp[4], a5 = rp[5];
        vm0 = fmaxf(vm0, fmaxf(fmaxf(a0, a1), a2));
        vm1 = fmaxf(vm1, fmaxf(fmaxf(a1, a2), a3));
        vm2 = fmaxf(vm2, fmaxf(fmaxf(a2, a3), a4));
        vm3 = fmaxf(vm3, fmaxf(fmaxf(a3, a4), a5));
    }

    const size_t pix0 = (size_t)b * HH * WW + (size_t)(by + ty) * WW + (bx + x0);
    const float4 pr = *(const float4*)(pre + pix0);
    const float vms[4] = {vm0, vm1, vm2, vm3};
    const float prs[4] = {pr.x, pr.y, pr.z, pr.w};
    #pragma unroll
    for (int j = 0; j < 4; ++j) {
        if (!(vms[j] > 0.1f && prs[j] > 0.5f)) {
            float4 z = make_float4(0.f, 0.f, 0.f, 0.f);
            float4* o4 = (float4*)(out + (pix0 + j) * CC);
            o4[0] = z; o4[1] = z; o4[2] = z; o4[3] = z;
        }
    }
}

extern "C" void kernel_launch(void* const* d_in, const int* in_sizes, int n_in,
                              void* d_out, int out_size, void* d_ws, size_t ws_size,
                              hipStream_t stream) {
    const float* x  = (const float*)d_in[0];
    const float* w0 = (const float*)d_in[1];
    const float* w1 = (const float*)d_in[2];
    const float* rm = (const float*)d_in[3];
    float* out = (float*)d_out;

    float* ws    = (float*)d_ws;
    float* alpha = ws;                         // B*H*W floats
    float* pre   = ws + NPIX;                  // B*H*W floats
    unsigned short* w0e = (unsigned short*)(ws + 2 * NPIX);  // 128*160 bf16
    unsigned short* w1b = w0e + HID * KEXP;                  // 16*128 bf16

    prep<<<(HID * KEXP + 255) / 256, 256, 0, stream>>>(w0, w1, w0e, w1b);

    dim3 grid(WW / TS, HH / TS, BB);
    dim3 blk(TS, TS);
    pass1<<<grid, blk, 0, stream>>>(x, w0e, w1b, rm, out, alpha, pre);

    dim3 grid2(WW / P2W, HH / P2H, BB);
    pass2<<<grid2, dim3(16, 16), 0, stream>>>(alpha, pre, out);
}